// Round 3
// baseline (4551.486 us; speedup 1.0000x reference)
//
#include <hip/hip_runtime.h>
#include <hip/hip_fp16.h>

namespace {

constexpr int kIn     = 64;
constexpr int kHid    = 128;
constexpr int kOut    = 64;
constexpr int kT      = 1000;
constexpr int kTC     = 8;
constexpr int kChunks = kT / kTC;   // 125
constexpr int kBatch  = 256;

__device__ __forceinline__ float sigm(float v)   { return 1.0f / (1.0f + __expf(-v)); }
__device__ __forceinline__ float tanhf_(float v) { return 2.0f / (1.0f + __expf(-2.0f * v)) - 1.0f; }

// XOR-swizzle of 16B chunks (involution) for f32 state arrays.
__device__ __forceinline__ int swzi(int i) { const int c = i >> 2; return ((c ^ ((c >> 3) & 7)) << 2) | (i & 3); }
__device__ __forceinline__ int swzc(int c) { return (c ^ ((c >> 3) & 7)) << 2; }
// column-local mapping produced by rs8
__device__ __forceinline__ int cl8(int k) { return ((k & 1) << 2) | (k & 2) | ((k >> 2) & 1); }

__device__ __forceinline__ float pack2f(float a, float b) {
  return __builtin_bit_cast(float, __floats2half2_rn(a, b));
}

// reduce-scatter 8 accumulators across 8 lanes (lane bits = kl); lane ends with
// the full sum for column cl8(kl).
__device__ __forceinline__ float rs8(float a0, float a1, float a2, float a3,
                                     float a4, float a5, float a6, float a7, int kl) {
  float t0, t1, t2, t3;
  {
    const bool hi = kl & 1;
    const float s0 = hi ? a0 : a4, s1 = hi ? a1 : a5, s2 = hi ? a2 : a6, s3 = hi ? a3 : a7;
    t0 = (hi ? a4 : a0) + __shfl_xor(s0, 1);
    t1 = (hi ? a5 : a1) + __shfl_xor(s1, 1);
    t2 = (hi ? a6 : a2) + __shfl_xor(s2, 1);
    t3 = (hi ? a7 : a3) + __shfl_xor(s3, 1);
  }
  float u0, u1;
  {
    const bool hi = kl & 2;
    const float s0 = hi ? t0 : t2, s1 = hi ? t1 : t3;
    u0 = (hi ? t2 : t0) + __shfl_xor(s0, 2);
    u1 = (hi ? t3 : t1) + __shfl_xor(s1, 2);
  }
  {
    const bool hi = kl & 4;
    const float s = hi ? u0 : u1;
    return (hi ? u1 : u0) + __shfl_xor(s, 4);
  }
}

// 2 accumulators (cols 2g, 2g+1) over 8 lanes; lane l ends with the full sum
// of col 2g + ((l>>2)&1).
__device__ __forceinline__ float rs2_8(float a0, float a1, int l) {
  const bool hi = (l & 4) != 0;
  const float send = hi ? a0 : a1;
  float v = (hi ? a1 : a0) + __shfl_xor(send, 4);
  v += __shfl_xor(v, 1);
  v += __shfl_xor(v, 2);
  return v;
}

// 8-MAC f16-weight quad dot: w holds 4 half2 pairs for k0..k0+7; a=[k0,k0+4), b=[k0+4,k0+8)
__device__ __forceinline__ float dotq(float4 w, float4 a, float4 b, float s) {
  const __half2 w0 = __builtin_bit_cast(__half2, w.x), w1 = __builtin_bit_cast(__half2, w.y),
                w2 = __builtin_bit_cast(__half2, w.z), w3 = __builtin_bit_cast(__half2, w.w);
  s = fmaf(__low2float(w0), a.x, s); s = fmaf(__high2float(w0), a.y, s);
  s = fmaf(__low2float(w1), a.z, s); s = fmaf(__high2float(w1), a.w, s);
  s = fmaf(__low2float(w2), b.x, s); s = fmaf(__high2float(w2), b.y, s);
  s = fmaf(__low2float(w3), b.z, s); s = fmaf(__high2float(w3), b.w, s);
  return s;
}

// 512 threads = 8 waves = 2 waves/EU (VGPR budget 256, TLP latency hiding).
// 2-barrier timestep:
//   SEG_A: z-dots (waves 0-3) / r-dots (waves 4-7) from su window; HA dot (all,
//          result kept IN REGISTER by its owner lane); publish szg, srh.
//   SEG_B: HH dot + rs2_8; gamma_h(t+1) team-dot (2 shuffle rounds, overlaps);
//          owner lanes (tid&3==0): h update, publish sh2/su_gh, store outH;
//          odd lanes: y(t-1) quarter-dots; lanes tid&3==2,<256: gamma_x+x'(t+1);
//          lanes tid&3==2,>=256: input staging (3 planes each).
__global__ __attribute__((amdgpu_flat_work_group_size(512, 512),
                          amdgpu_waves_per_eu(2, 2)))
void grud_persistent(
    const float* __restrict__ gIn,
    const float* __restrict__ xMean,
    const float* __restrict__ Wdgx, const float* __restrict__ bdgx,
    const float* __restrict__ Wdgh, const float* __restrict__ bdgh,
    const float* __restrict__ Wxz,  const float* __restrict__ Whz,
    const float* __restrict__ Wmz,  const float* __restrict__ bmz,
    const float* __restrict__ Wxr,  const float* __restrict__ Whr,
    const float* __restrict__ Wmr,
    const float* __restrict__ Wxh,  const float* __restrict__ Whh,
    const float* __restrict__ Wmh,  const float* __restrict__ bmh,
    const float* __restrict__ Why,  const float* __restrict__ bhy,
    float* __restrict__ out)
{
  const int tid = threadIdx.x;
  const int b   = blockIdx.x;

  __shared__ __align__(16) float sX[2][kTC][kIn];
  __shared__ __align__(16) float sM[2][kTC][kIn];
  __shared__ __align__(16) float sD[2][kTC][kIn];
  __shared__ __align__(16) float su[2 * kHid];    // swizzled: [x'|m|gh*h]
  __shared__ __align__(16) float sh2[2 * kHid];   // parity-double-buffered h
  __shared__ __align__(16) float srh[kHid];       // swizzled
  __shared__ __align__(16) float szg[kHid];       // swizzled
  __shared__ __align__(16) float4 lwDGH[kHid * 8]; // Wdgh f16 quads, swizzled
  __shared__ __align__(16) float4 lwDGX[kIn * 8];  // Wdgx
  __shared__ __align__(16) float4 lwHY[kOut * 16]; // Why

  // ---------------- role coordinates ----------------
  const int lt256 = tid & 255;
  const int kc  = lt256 & 15;            // z/r K-chunk (16 floats)
  const int cg  = lt256 >> 4;            // z/r col-group (8 cols)
  const bool isZ = tid < 256;
  const int kc8 = tid & 7;               // HA/HH K-chunk
  const int hg  = tid >> 3;              // HA/HH col-pair group
  const int kq  = tid & 3;               // gamma_h team K-chunk
  const int jh  = 2 * hg + (kc8 >> 2);   // column this lane ends up holding
  const bool isOwner = (kc8 & 3) == 0;
  const bool isX = ((tid & 3) == 2) && (tid < 256);
  const bool isS = ((tid & 3) == 2) && (tid >= 256);
  const int cx  = tid >> 2;              // x-column (valid for isX)
  const int si  = lt256 >> 2;            // staging row i (valid for isS)
  const int lty = (tid >> 2) * 2 + ((tid & 3) >> 1);  // odd lanes: y index
  const int oy  = lty >> 2;              // y output column
  const int qy  = lty & 3;               // y K-quarter

  // ---------------- register weights (hot: z|r, HA, HH) ----------------
  __half2 wZR[8][8];   // z (tid<256) or r (tid>=256): 8 cols x 16 k
  __half2 wHA[2][8];   // [Wxh;Wmh]: 2 cols x 16 k
  __half2 wHH[2][8];   // Whh
  {
    const float* Wx = isZ ? Wxz : Wxr;
    const float* Wm = isZ ? Wmz : Wmr;
    const float* Wh = isZ ? Whz : Whr;
#pragma unroll
    for (int c = 0; c < 8; ++c) {
      const int j = cg * 8 + c;
#pragma unroll
      for (int p = 0; p < 8; ++p) {
        const int k = kc * 16 + 2 * p;
        const float a0 = (k < 64) ? Wx[k * kHid + j]
                        : (k < 128) ? Wm[(k - 64) * kHid + j]
                                    : Wh[(k - 128) * kHid + j];
        const float a1 = (k + 1 < 64) ? Wx[(k + 1) * kHid + j]
                        : (k + 1 < 128) ? Wm[(k + 1 - 64) * kHid + j]
                                        : Wh[(k + 1 - 128) * kHid + j];
        wZR[c][p] = __floats2half2_rn(a0, a1);
      }
    }
  }
#pragma unroll
  for (int c = 0; c < 2; ++c) {
    const int j = 2 * hg + c;
#pragma unroll
    for (int p = 0; p < 8; ++p) {
      const int k = kc8 * 16 + 2 * p;
      const float h0 = (k < 64) ? Wxh[k * kHid + j] : Wmh[(k - 64) * kHid + j];
      const float h1 = (k + 1 < 64) ? Wxh[(k + 1) * kHid + j] : Wmh[(k + 1 - 64) * kHid + j];
      wHA[c][p] = __floats2half2_rn(h0, h1);
      wHH[c][p] = __floats2half2_rn(Whh[k * kHid + j], Whh[(k + 1) * kHid + j]);
    }
  }

  // ---------------- LDS f16 weights (cold), writer == future reader ----------------
#pragma unroll
  for (int q = 0; q < 2; ++q) {          // Wdgh: col jh, k-chunk kq
    const int k0 = kq * 16 + q * 8;
    float4 wv;
    wv.x = pack2f(Wdgh[(k0 + 0) * kHid + jh], Wdgh[(k0 + 1) * kHid + jh]);
    wv.y = pack2f(Wdgh[(k0 + 2) * kHid + jh], Wdgh[(k0 + 3) * kHid + jh]);
    wv.z = pack2f(Wdgh[(k0 + 4) * kHid + jh], Wdgh[(k0 + 5) * kHid + jh]);
    wv.w = pack2f(Wdgh[(k0 + 6) * kHid + jh], Wdgh[(k0 + 7) * kHid + jh]);
    const int idx = jh * 8 + kq * 2 + q;
    lwDGH[(idx & ~7) | ((idx & 7) ^ (jh & 7))] = wv;
  }
  if (isX) {
#pragma unroll
    for (int j = 0; j < 8; ++j) {        // Wdgx: col cx, full K
      const int k0 = j * 8;
      float4 wv;
      wv.x = pack2f(Wdgx[(k0 + 0) * kIn + cx], Wdgx[(k0 + 1) * kIn + cx]);
      wv.y = pack2f(Wdgx[(k0 + 2) * kIn + cx], Wdgx[(k0 + 3) * kIn + cx]);
      wv.z = pack2f(Wdgx[(k0 + 4) * kIn + cx], Wdgx[(k0 + 5) * kIn + cx]);
      wv.w = pack2f(Wdgx[(k0 + 6) * kIn + cx], Wdgx[(k0 + 7) * kIn + cx]);
      lwDGX[(cx << 3) | (j ^ (cx & 7))] = wv;
    }
  }
  if (tid & 1) {
#pragma unroll
    for (int j = 0; j < 4; ++j) {        // Why: col oy, K-quarter qy
      const int k0 = qy * 32 + j * 8;
      float4 wv;
      wv.x = pack2f(Why[(k0 + 0) * kOut + oy], Why[(k0 + 1) * kOut + oy]);
      wv.y = pack2f(Why[(k0 + 2) * kOut + oy], Why[(k0 + 3) * kOut + oy]);
      wv.z = pack2f(Why[(k0 + 4) * kOut + oy], Why[(k0 + 5) * kOut + oy]);
      wv.w = pack2f(Why[(k0 + 6) * kOut + oy], Why[(k0 + 7) * kOut + oy]);
      const int blk = oy * 2 + (qy >> 1);
      lwHY[(blk << 3) | ((((qy & 1) << 2) | j) ^ (blk & 7))] = wv;
    }
  }

  // ---------------- loop-invariant constants ----------------
  const int   jz      = cg * 8 + cl8(kc & 7);
  const float bZv     = bmz[jz];
  const int   idxZ    = swzi(jz);
  const int   idxZgh  = swzi(128 + jz);
  const float bHAv    = bmh[jh];
  const float bGHv    = bdgh[jh];
  const int   idxJh   = swzi(jh);
  const int   idxJhGh = swzi(128 + jh);
  const float bGXv    = isX ? bdgx[cx] : 0.0f;
  const float xmv     = isX ? xMean[cx] : 0.0f;
  const int   idxXw   = swzi(cx & 63);
  const int   idxMw   = swzi(64 + (cx & 63));
  const float bYv     = bhy[oy];

  int suOff[4], haOff[4];
#pragma unroll
  for (int q = 0; q < 4; ++q) {
    suOff[q] = swzc(kc * 4 + q);    // su window (K=256)
    haOff[q] = swzc(kc8 * 4 + q);   // su[0:128] / srh window (K=128)
  }

  const float* gBase = gIn + (size_t)b * 3 * kIn * kT;
  float* outY = out + (size_t)b * kT * kOut;
  float* outH = out + (size_t)kBatch * kT * kOut + (size_t)b * kT * kHid;

  // ---------------- prologue ----------------
  float4 sv0a = {}, sv0b = {}, sv1a = {}, sv1b = {}, sv2a = {}, sv2b = {};
  if (isS) {                              // stage chunk 0 directly
    const float4* p0 = reinterpret_cast<const float4*>(gBase + (size_t)(0 * kIn + si) * kT);
    const float4* p1 = reinterpret_cast<const float4*>(gBase + (size_t)(1 * kIn + si) * kT);
    const float4* p2 = reinterpret_cast<const float4*>(gBase + (size_t)(2 * kIn + si) * kT);
    const float4 a0 = p0[0], a1 = p0[1], b0 = p1[0], b1 = p1[1], c0 = p2[0], c1 = p2[1];
    sX[0][0][si] = a0.x; sX[0][1][si] = a0.y; sX[0][2][si] = a0.z; sX[0][3][si] = a0.w;
    sX[0][4][si] = a1.x; sX[0][5][si] = a1.y; sX[0][6][si] = a1.z; sX[0][7][si] = a1.w;
    sM[0][0][si] = b0.x; sM[0][1][si] = b0.y; sM[0][2][si] = b0.z; sM[0][3][si] = b0.w;
    sM[0][4][si] = b1.x; sM[0][5][si] = b1.y; sM[0][6][si] = b1.z; sM[0][7][si] = b1.w;
    sD[0][0][si] = c0.x; sD[0][1][si] = c0.y; sD[0][2][si] = c0.z; sD[0][3][si] = c0.w;
    sD[0][4][si] = c1.x; sD[0][5][si] = c1.y; sD[0][6][si] = c1.z; sD[0][7][si] = c1.w;
  }
  if (tid < 128) su[128 + tid] = 0.0f;    // gh*h(-1) = 0 (covers swizzled range)
  __syncthreads();

  float xl = 0.0f;
  if (isX) {                              // x'(0)
    const float* dRow = &sD[0][0][0];
    float s = 0.0f;
#pragma unroll
    for (int j = 0; j < 8; ++j) {
      const float4 w  = lwDGX[(cx << 3) | (j ^ (cx & 7))];
      const float4 d0 = *reinterpret_cast<const float4*>(dRow + j * 8);
      const float4 d1 = *reinterpret_cast<const float4*>(dRow + j * 8 + 4);
      s = dotq(w, d0, d1, s);
    }
    const float gx = __expf(-fmaxf(s + bGXv, 0.0f));
    const float xv = sX[0][0][cx], mv = sM[0][0][cx];
    xl = (mv > 0.0f) ? xv : 0.0f;
    su[idxXw] = mv * xv + (1.0f - mv) * (gx * xl + (1.0f - gx) * xmv);
    su[idxMw] = mv;
  }
  __syncthreads();

  // ---------------- main loop ----------------
#pragma unroll 1
  for (int t = 0; t < kT; ++t) {
    const int tt = t & 7;

    // ========== SEG_A: z|r dots + HA dot ==========
    float hav;
    {
      float u[16];
      {
        const float4 c0 = *reinterpret_cast<const float4*>(su + suOff[0]);
        const float4 c1 = *reinterpret_cast<const float4*>(su + suOff[1]);
        const float4 c2 = *reinterpret_cast<const float4*>(su + suOff[2]);
        const float4 c3 = *reinterpret_cast<const float4*>(su + suOff[3]);
        u[0]=c0.x;  u[1]=c0.y;  u[2]=c0.z;  u[3]=c0.w;
        u[4]=c1.x;  u[5]=c1.y;  u[6]=c1.z;  u[7]=c1.w;
        u[8]=c2.x;  u[9]=c2.y;  u[10]=c2.z; u[11]=c2.w;
        u[12]=c3.x; u[13]=c3.y; u[14]=c3.z; u[15]=c3.w;
      }
      float acc[8];
#pragma unroll
      for (int c = 0; c < 8; ++c) {
        float s = 0.0f;
#pragma unroll
        for (int p = 0; p < 8; ++p) {
          s = fmaf(__low2float(wZR[c][p]),  u[2 * p],     s);
          s = fmaf(__high2float(wZR[c][p]), u[2 * p + 1], s);
        }
        acc[c] = s;
      }
      float zr = rs8(acc[0], acc[1], acc[2], acc[3], acc[4], acc[5], acc[6], acc[7], kc & 7);
      zr += __shfl_xor(zr, 8);

      float v[16];
      {
        const float4 c0 = *reinterpret_cast<const float4*>(su + haOff[0]);
        const float4 c1 = *reinterpret_cast<const float4*>(su + haOff[1]);
        const float4 c2 = *reinterpret_cast<const float4*>(su + haOff[2]);
        const float4 c3 = *reinterpret_cast<const float4*>(su + haOff[3]);
        v[0]=c0.x;  v[1]=c0.y;  v[2]=c0.z;  v[3]=c0.w;
        v[4]=c1.x;  v[5]=c1.y;  v[6]=c1.z;  v[7]=c1.w;
        v[8]=c2.x;  v[9]=c2.y;  v[10]=c2.z; v[11]=c2.w;
        v[12]=c3.x; v[13]=c3.y; v[14]=c3.z; v[15]=c3.w;
      }
      float a0 = 0.0f, a1 = 0.0f;
#pragma unroll
      for (int p = 0; p < 8; ++p) {
        a0 = fmaf(__low2float(wHA[0][p]),  v[2 * p],     a0);
        a0 = fmaf(__high2float(wHA[0][p]), v[2 * p + 1], a0);
        a1 = fmaf(__low2float(wHA[1][p]),  v[2 * p],     a1);
        a1 = fmaf(__high2float(wHA[1][p]), v[2 * p + 1], a1);
      }
      hav = rs2_8(a0, a1, kc8) + bHAv;   // stays in register; this lane owns col jh

      if (isZ) { if (kc < 8) szg[idxZ] = sigm(zr + bZv); }
      else     { if (kc < 8) srh[idxZ] = sigm(zr) * su[idxZgh]; }
    }
    __syncthreads();

    // ========== SEG_B: HH + gamma(t+1) + h update + y(t-1) + x'(t+1) + staging ==========
    {
      const int tn = t + 1, ttN = tn & 7, bufN = (tn >> 3) & 1;

      // gamma_h(t+1) team dot (4 lanes, K-split 16) — overlaps HH reduce
      float gdh;
      {
        const float* dRow = &sD[bufN][ttN][0];
        float s = 0.0f;
#pragma unroll
        for (int q = 0; q < 2; ++q) {
          const int idx = jh * 8 + kq * 2 + q;
          const float4 w  = lwDGH[(idx & ~7) | ((idx & 7) ^ (jh & 7))];
          const float4 d0 = *reinterpret_cast<const float4*>(dRow + kq * 16 + q * 8);
          const float4 d1 = *reinterpret_cast<const float4*>(dRow + kq * 16 + q * 8 + 4);
          s = dotq(w, d0, d1, s);
        }
        s += __shfl_xor(s, 1);
        s += __shfl_xor(s, 2);
        gdh = s;
      }

      // HH dot
      float w16[16];
      {
        const float4 c0 = *reinterpret_cast<const float4*>(srh + haOff[0]);
        const float4 c1 = *reinterpret_cast<const float4*>(srh + haOff[1]);
        const float4 c2 = *reinterpret_cast<const float4*>(srh + haOff[2]);
        const float4 c3 = *reinterpret_cast<const float4*>(srh + haOff[3]);
        w16[0]=c0.x;  w16[1]=c0.y;  w16[2]=c0.z;  w16[3]=c0.w;
        w16[4]=c1.x;  w16[5]=c1.y;  w16[6]=c1.z;  w16[7]=c1.w;
        w16[8]=c2.x;  w16[9]=c2.y;  w16[10]=c2.z; w16[11]=c2.w;
        w16[12]=c3.x; w16[13]=c3.y; w16[14]=c3.z; w16[15]=c3.w;
      }
      float b0 = 0.0f, b1 = 0.0f;
#pragma unroll
      for (int p = 0; p < 8; ++p) {
        b0 = fmaf(__low2float(wHH[0][p]),  w16[2 * p],     b0);
        b0 = fmaf(__high2float(wHH[0][p]), w16[2 * p + 1], b0);
        b1 = fmaf(__low2float(wHH[1][p]),  w16[2 * p],     b1);
        b1 = fmaf(__high2float(wHH[1][p]), w16[2 * p + 1], b1);
      }
      const float hh = rs2_8(b0, b1, kc8);

      if (isOwner) {
        const float zz = szg[idxJh];
        const float hp = su[idxJhGh];                 // old gh*h (this step's input)
        const float hn = (1.0f - zz) * hp + zz * tanhf_(hav + hh);
        sh2[((t & 1) << 7) + idxJh] = hn;
        outH[(size_t)t * kHid + jh] = hn;
        su[idxJhGh] = __expf(-fmaxf(gdh + bGHv, 0.0f)) * hn;  // gh(t+1)*h(t)
      }

      if (tid & 1) {                                  // y(t-1) quarter-dot
        if (t > 0) {
          const float* shb = sh2 + (((t - 1) & 1) << 7);
          float s = 0.0f;
#pragma unroll
          for (int j = 0; j < 4; ++j) {
            const int blk = oy * 2 + (qy >> 1);
            const float4 w  = lwHY[(blk << 3) | ((((qy & 1) << 2) | j) ^ (blk & 7))];
            const float4 h0 = *reinterpret_cast<const float4*>(shb + (((qy << 3) | ((2 * j) ^ qy)) << 2));
            const float4 h1 = *reinterpret_cast<const float4*>(shb + (((qy << 3) | ((2 * j + 1) ^ qy)) << 2));
            s = dotq(w, h0, h1, s);
          }
          s += __shfl_xor(s, 2);
          s += __shfl_xor(s, 4);
          if ((tid & 7) == 1) outY[(size_t)(t - 1) * kOut + oy] = sigm(s + bYv);
        }
      } else if (isX) {                               // gamma_x + x'(t+1)
        const float* dRow = &sD[bufN][ttN][0];
        float s = 0.0f;
#pragma unroll
        for (int j = 0; j < 8; ++j) {
          const float4 w  = lwDGX[(cx << 3) | (j ^ (cx & 7))];
          const float4 d0 = *reinterpret_cast<const float4*>(dRow + j * 8);
          const float4 d1 = *reinterpret_cast<const float4*>(dRow + j * 8 + 4);
          s = dotq(w, d0, d1, s);
        }
        const float gx = __expf(-fmaxf(s + bGXv, 0.0f));
        const float xv = sX[bufN][ttN][cx], mv = sM[bufN][ttN][cx];
        xl = (mv > 0.0f) ? xv : xl;
        su[idxXw] = mv * xv + (1.0f - mv) * (gx * xl + (1.0f - gx) * xmv);
        su[idxMw] = mv;
      } else if (isS) {                               // staging (3 planes)
        if (tt == 7) {
          const int cs = (t >> 3) + 2;
          if (cs < kChunks) {
            const float4* p0 = reinterpret_cast<const float4*>(gBase + (size_t)(0 * kIn + si) * kT + cs * kTC);
            const float4* p1 = reinterpret_cast<const float4*>(gBase + (size_t)(1 * kIn + si) * kT + cs * kTC);
            const float4* p2 = reinterpret_cast<const float4*>(gBase + (size_t)(2 * kIn + si) * kT + cs * kTC);
            sv0a = p0[0]; sv0b = p0[1];
            sv1a = p1[0]; sv1b = p1[1];
            sv2a = p2[0]; sv2b = p2[1];
          }
        } else if (tt == 0 && t > 0) {
          const int cs = (t >> 3) + 1;
          if (cs < kChunks) {
            const int bw = cs & 1;
            sX[bw][0][si] = sv0a.x; sX[bw][1][si] = sv0a.y; sX[bw][2][si] = sv0a.z; sX[bw][3][si] = sv0a.w;
            sX[bw][4][si] = sv0b.x; sX[bw][5][si] = sv0b.y; sX[bw][6][si] = sv0b.z; sX[bw][7][si] = sv0b.w;
            sM[bw][0][si] = sv1a.x; sM[bw][1][si] = sv1a.y; sM[bw][2][si] = sv1a.z; sM[bw][3][si] = sv1a.w;
            sM[bw][4][si] = sv1b.x; sM[bw][5][si] = sv1b.y; sM[bw][6][si] = sv1b.z; sM[bw][7][si] = sv1b.w;
            sD[bw][0][si] = sv2a.x; sD[bw][1][si] = sv2a.y; sD[bw][2][si] = sv2a.z; sD[bw][3][si] = sv2a.w;
            sD[bw][4][si] = sv2b.x; sD[bw][5][si] = sv2b.y; sD[bw][6][si] = sv2b.z; sD[bw][7][si] = sv2b.w;
          }
        }
      }
      if (tt == 0 && t == 0 && isS) {                 // cold start: chunk 1 direct
        const int cs = 1;
        const float4* p0 = reinterpret_cast<const float4*>(gBase + (size_t)(0 * kIn + si) * kT + cs * kTC);
        const float4* p1 = reinterpret_cast<const float4*>(gBase + (size_t)(1 * kIn + si) * kT + cs * kTC);
        const float4* p2 = reinterpret_cast<const float4*>(gBase + (size_t)(2 * kIn + si) * kT + cs * kTC);
        const float4 a0 = p0[0], a1 = p0[1], q0 = p1[0], q1 = p1[1], d0 = p2[0], d1 = p2[1];
        sX[1][0][si] = a0.x; sX[1][1][si] = a0.y; sX[1][2][si] = a0.z; sX[1][3][si] = a0.w;
        sX[1][4][si] = a1.x; sX[1][5][si] = a1.y; sX[1][6][si] = a1.z; sX[1][7][si] = a1.w;
        sM[1][0][si] = q0.x; sM[1][1][si] = q0.y; sM[1][2][si] = q0.z; sM[1][3][si] = q0.w;
        sM[1][4][si] = q1.x; sM[1][5][si] = q1.y; sM[1][6][si] = q1.z; sM[1][7][si] = q1.w;
        sD[1][0][si] = d0.x; sD[1][1][si] = d0.y; sD[1][2][si] = d0.z; sD[1][3][si] = d0.w;
        sD[1][4][si] = d1.x; sD[1][5][si] = d1.y; sD[1][6][si] = d1.z; sD[1][7][si] = d1.w;
      }
    }
    __syncthreads();
  }

  // epilogue: y(999)
  if (tid & 1) {
    const float* shb = sh2 + (((kT - 1) & 1) << 7);
    float s = 0.0f;
#pragma unroll
    for (int j = 0; j < 4; ++j) {
      const int blk = oy * 2 + (qy >> 1);
      const float4 w  = lwHY[(blk << 3) | ((((qy & 1) << 2) | j) ^ (blk & 7))];
      const float4 h0 = *reinterpret_cast<const float4*>(shb + (((qy << 3) | ((2 * j) ^ qy)) << 2));
      const float4 h1 = *reinterpret_cast<const float4*>(shb + (((qy << 3) | ((2 * j + 1) ^ qy)) << 2));
      s = dotq(w, h0, h1, s);
    }
    s += __shfl_xor(s, 2);
    s += __shfl_xor(s, 4);
    if ((tid & 7) == 1) outY[(size_t)(kT - 1) * kOut + oy] = sigm(s + bYv);
  }
}

} // namespace

extern "C" void kernel_launch(void* const* d_in, const int* in_sizes, int n_in,
                              void* d_out, int out_size, void* d_ws, size_t ws_size,
                              hipStream_t stream) {
  const float* gIn   = (const float*)d_in[0];
  const float* xMean = (const float*)d_in[1];
  const float* Wdgx  = (const float*)d_in[2];
  const float* bdgx  = (const float*)d_in[3];
  const float* Wdgh  = (const float*)d_in[4];
  const float* bdgh  = (const float*)d_in[5];
  const float* Wxz   = (const float*)d_in[6];
  const float* Whz   = (const float*)d_in[7];
  const float* Wmz   = (const float*)d_in[8];
  const float* bmz   = (const float*)d_in[9];
  const float* Wxr   = (const float*)d_in[10];
  const float* Whr   = (const float*)d_in[11];
  const float* Wmr   = (const float*)d_in[12];
  const float* Wxh   = (const float*)d_in[13];
  const float* Whh   = (const float*)d_in[14];
  const float* Wmh   = (const float*)d_in[15];
  const float* bmh   = (const float*)d_in[16];
  const float* Why   = (const float*)d_in[17];
  const float* bhy   = (const float*)d_in[18];

  grud_persistent<<<dim3(256), dim3(512), 0, stream>>>(
      gIn, xMean, Wdgx, bdgx, Wdgh, bdgh, Wxz, Whz, Wmz, bmz,
      Wxr, Whr, Wmr, Wxh, Whh, Wmh, bmh, Why, bhy, (float*)d_out);
}